// Round 3
// baseline (64.555 us; speedup 1.0000x reference)
//
#include <hip/hip_runtime.h>
#include <hip/hip_bf16.h>

// Problem: B=8192, DIM_IN=2048, DIM_OUT=512
//   hazards = relu(x @ W_h^T + b_h)            [8192,512]
//   out     = cumsum(hazards, axis=1) + (x @ W_base^T + b_base)
//
// Round 3: double-buffered LDS (1 barrier/K-step), depth-2 register prefetch
// (compiler emits counted vmcnt), swapped-operand MFMA for float4 epilogue.

typedef __attribute__((ext_vector_type(8))) short  short8;
typedef __attribute__((ext_vector_type(4))) short  short4v;
typedef __attribute__((ext_vector_type(4))) float  float4v;
typedef __attribute__((ext_vector_type(4))) float  f32x4;

#define DIN  2048
#define DOUT 512
#define NROW 8192
#define NKT  (DIN / 64)

static __device__ __forceinline__ unsigned short f2bf(float f) {
  union { float f; unsigned int u; } v; v.f = f;
  unsigned int u = v.u;
  unsigned int r = (u + 0x7FFFu + ((u >> 16) & 1u)) >> 16;   // RNE
  return (unsigned short)r;
}
static __device__ __forceinline__ float bf2f(unsigned short u) {
  union { unsigned int u; float f; } v; v.u = ((unsigned int)u) << 16;
  return v.f;
}

// ---------------- kernel 1: cast W_hazard [512][2048] f32 -> bf16 ----------
__global__ __launch_bounds__(256) void k_cast(const float* __restrict__ W,
                                              unsigned short* __restrict__ Wb) {
  size_t i = ((size_t)blockIdx.x * 256 + threadIdx.x) * 8;
  float4v a = *(const float4v*)(W + i);
  float4v b = *(const float4v*)(W + i + 4);
  unsigned short o[8] = { f2bf(a.x), f2bf(a.y), f2bf(a.z), f2bf(a.w),
                          f2bf(b.x), f2bf(b.y), f2bf(b.z), f2bf(b.w) };
  *(short8*)(Wb + i) = *(const short8*)o;
}

// ---------------- kernel 2: GEMM + bias + relu + base GEMV -----------------
// tile 64x64, BK=64; 256 threads = 4 waves (2x2) of 32x32 output each.
// LDS XOR-swizzle: 16B granule g of row r stored at g ^ (r&7)   (row = 128B).
__global__ __launch_bounds__(256, 4) void k_gemm(
    const float* __restrict__ x, const unsigned short* __restrict__ Wb,
    const float* __restrict__ b_h, const float* __restrict__ w_base,
    const float* __restrict__ b_base, float* __restrict__ hz,
    float* __restrict__ base_out) {
  __shared__ unsigned short Asw[2][64 * 64];   // 2 x 8 KB
  __shared__ unsigned short Bsw[2][64 * 64];   // 2 x 8 KB
  __shared__ float WbL[DIN];                   // 8 KB (base GEMV weights)

  const int tid  = threadIdx.x;
  const int lane = tid & 63;
  const int wv   = tid >> 6;
  const int wr   = wv >> 1, wc = wv & 1;

  // XCD-chunked bijective swizzle: nwg=1024 -> 128 blocks per XCD chunk;
  // bj (N-tile) fastest within a chunk so A-panel sharers co-reside per XCD.
  const int id  = blockIdx.x;
  const int swz = ((id & 7) << 7) | (id >> 3);
  const int bi  = swz >> 3;          // 0..127  M-tile
  const int bj  = swz & 7;           // 0..7    N-tile
  const int m0  = bi * 64, n0 = bj * 64;
  const bool do_base = (bj == 0);

  if (do_base) {
    for (int i = tid; i < DIN; i += 256) WbL[i] = w_base[i];
  }

  // staging: thread t -> row t>>2, 16-elem column block t&3
  const int sr = tid >> 2;
  const int sc = (tid & 3) * 16;
  const int g0 = (tid & 3) * 2;
  const int offS0 = sr * 64 + (((g0)     ^ (sr & 7)) << 3);
  const int offS1 = sr * 64 + (((g0 + 1) ^ (sr & 7)) << 3);

  f32x4 acc[2][2];
  const f32x4 zero4 = {0.f, 0.f, 0.f, 0.f};
#pragma unroll
  for (int mi = 0; mi < 2; ++mi)
#pragma unroll
    for (int ni = 0; ni < 2; ++ni) acc[mi][ni] = zero4;

  struct Tile { float4v a[4]; short8 b[2]; };
  Tile t0, t1;

  auto load_tile = [&](Tile& T, int kt) {
    const int k0 = kt * 64;
    const float* ap = x + (size_t)(m0 + sr) * DIN + k0 + sc;
#pragma unroll
    for (int p = 0; p < 4; ++p) T.a[p] = *(const float4v*)(ap + p * 4);
    const unsigned short* bp = Wb + (size_t)(n0 + sr) * DIN + k0 + sc;
    T.b[0] = *(const short8*)bp;
    T.b[1] = *(const short8*)(bp + 8);
  };

  auto write_tile = [&](unsigned short* As, unsigned short* Bs, const Tile& T) {
    unsigned short t8[16];
#pragma unroll
    for (int p = 0; p < 4; ++p) {
      t8[p * 4 + 0] = f2bf(T.a[p].x); t8[p * 4 + 1] = f2bf(T.a[p].y);
      t8[p * 4 + 2] = f2bf(T.a[p].z); t8[p * 4 + 3] = f2bf(T.a[p].w);
    }
    *(short8*)&As[offS0] = *(const short8*)&t8[0];
    *(short8*)&As[offS1] = *(const short8*)&t8[8];
    *(short8*)&Bs[offS0] = T.b[0];
    *(short8*)&Bs[offS1] = T.b[1];
  };

  float basePart = 0.f;
  const int bSeg = tid & 3;  // base GEMV: 4 threads per row (row = sr)

  auto compute = [&](const unsigned short* As, const unsigned short* Bs, int kt) {
#pragma unroll
    for (int kk = 0; kk < 2; ++kk) {
      short8 af[2], bfr[2];
#pragma unroll
      for (int mi = 0; mi < 2; ++mi) {
        int row = wr * 32 + mi * 16 + (lane & 15);
        int gr  = kk * 4 + (lane >> 4);
        af[mi] = *(const short8*)&As[row * 64 + ((gr ^ (row & 7)) << 3)];
      }
#pragma unroll
      for (int ni = 0; ni < 2; ++ni) {
        int col = wc * 32 + ni * 16 + (lane & 15);
        int gr  = kk * 4 + (lane >> 4);
        bfr[ni] = *(const short8*)&Bs[col * 64 + ((gr ^ (col & 7)) << 3)];
      }
      // swapped operands: D[n][m] so acc regs are 4 consecutive n (cols)
#pragma unroll
      for (int mi = 0; mi < 2; ++mi)
#pragma unroll
        for (int ni = 0; ni < 2; ++ni)
          acc[mi][ni] = __builtin_amdgcn_mfma_f32_16x16x32_bf16(
              bfr[ni], af[mi], acc[mi][ni], 0, 0, 0);
    }
    if (do_base) {  // base GEMV partial from staged A tile (bf16 precision)
      const int k0 = kt * 64;
      float p = 0.f;
#pragma unroll
      for (int j = 0; j < 2; ++j) {
        int g = bSeg * 2 + j;
        const short8 v = *(const short8*)&As[sr * 64 + ((g ^ (sr & 7)) << 3)];
#pragma unroll
        for (int e = 0; e < 8; ++e)
          p += bf2f((unsigned short)v[e]) * WbL[k0 + bSeg * 16 + j * 8 + e];
      }
      basePart += p;
    }
  };

  // prologue: fill buf0 with tile0; tile1 loads stay in flight
  load_tile(t0, 0);
  load_tile(t1, 1);
  write_tile(Asw[0], Bsw[0], t0);
  __syncthreads();

  for (int kt = 0; kt < NKT; kt += 2) {
    // phase A: compute tile kt (buf0); prefetch kt+2 into t0; write kt+1 -> buf1
    if (kt + 2 < NKT) load_tile(t0, kt + 2);
    compute(Asw[0], Bsw[0], kt);
    if (kt + 1 < NKT) write_tile(Asw[1], Bsw[1], t1);
    __syncthreads();
    // phase B: compute tile kt+1 (buf1); prefetch kt+3 into t1; write kt+2 -> buf0
    if (kt + 3 < NKT) load_tile(t1, kt + 3);
    if (kt + 1 < NKT) compute(Asw[1], Bsw[1], kt + 1);
    if (kt + 2 < NKT) write_tile(Asw[0], Bsw[0], t0);
    __syncthreads();
  }

  if (do_base) {
    float s = basePart;
    s += __shfl_xor(s, 1);
    s += __shfl_xor(s, 2);
    if ((tid & 3) == 0) base_out[m0 + sr] = s + b_base[0];
  }

  // epilogue: bias + relu -> hazards ws (float4 stores; acc regs = 4 cols)
#pragma unroll
  for (int mi = 0; mi < 2; ++mi) {
    int m = m0 + wr * 32 + mi * 16 + (lane & 15);
#pragma unroll
    for (int ni = 0; ni < 2; ++ni) {
      int nb = n0 + wc * 32 + ni * 16 + ((lane >> 4) << 2);
      float4v b4 = *(const float4v*)(b_h + nb);
      f32x4 v = acc[mi][ni];
      float4v o = { fmaxf(v.x + b4.x, 0.f), fmaxf(v.y + b4.y, 0.f),
                    fmaxf(v.z + b4.z, 0.f), fmaxf(v.w + b4.w, 0.f) };
      *(float4v*)(hz + (size_t)m * DOUT + nb) = o;
    }
  }
}

// ---------------- kernel 3: per-row inclusive scan + base ------------------
// 4 waves per block, one row per wave; lane holds 8 consecutive f32.
__global__ __launch_bounds__(256) void k_scan(const float* __restrict__ hz,
                                              const float* __restrict__ base,
                                              float* __restrict__ out) {
  const int tid  = threadIdx.x;
  const int lane = tid & 63;
  const int w    = tid >> 6;
  const int row  = blockIdx.x * 4 + w;

  const float* p = hz + (size_t)row * DOUT + lane * 8;
  float4v v0 = *(const float4v*)p;
  float4v v1 = *(const float4v*)(p + 4);

  float s0 = v0.x;
  float s1 = s0 + v0.y;
  float s2 = s1 + v0.z;
  float s3 = s2 + v0.w;
  float s4 = s3 + v1.x;
  float s5 = s4 + v1.y;
  float s6 = s5 + v1.z;
  float s7 = s6 + v1.w;

  float T = s7, sc = s7;
#pragma unroll
  for (int d = 1; d < 64; d <<= 1) {
    float t = __shfl_up(sc, d);
    if (lane >= d) sc += t;
  }
  float off = sc - T + base[row];

  float4v o0 = { s0 + off, s1 + off, s2 + off, s3 + off };
  float4v o1 = { s4 + off, s5 + off, s6 + off, s7 + off };
  float* q = out + (size_t)row * DOUT + lane * 8;
  *(float4v*)q       = o0;
  *(float4v*)(q + 4) = o1;
}

// ---------------------------------------------------------------------------
extern "C" void kernel_launch(void* const* d_in, const int* in_sizes, int n_in,
                              void* d_out, int out_size, void* d_ws, size_t ws_size,
                              hipStream_t stream) {
  const float* x   = (const float*)d_in[0];  // [8192,2048]
  const float* Wh  = (const float*)d_in[1];  // [512,2048]
  const float* bh  = (const float*)d_in[2];  // [512]
  const float* Wb0 = (const float*)d_in[3];  // [1,2048]
  const float* bb  = (const float*)d_in[4];  // [1]
  float* out = (float*)d_out;

  char* ws = (char*)d_ws;
  unsigned short* Wbf = (unsigned short*)ws;                        // 2 MiB
  float* base = (float*)(ws + 2u * 1024 * 1024);                    // 32 KiB
  float* hz   = (float*)(ws + 2u * 1024 * 1024 + 32u * 1024);       // 16 MiB

  k_cast<<<dim3((DOUT * DIN) / (256 * 8)), dim3(256), 0, stream>>>(Wh, Wbf);
  k_gemm<<<dim3(1024), dim3(256), 0, stream>>>(x, Wbf, bh, Wb0, bb, hz, base);
  k_scan<<<dim3(NROW / 4), dim3(256), 0, stream>>>(hz, base, out);
}

// Round 4
// 59.690 us; speedup vs baseline: 1.0815x; 1.0815x over previous
//
#include <hip/hip_runtime.h>
#include <hip/hip_bf16.h>

// Problem: B=8192, DIM_IN=2048, DIM_OUT=512
//   hazards = relu(x @ W_h^T + b_h)            [8192,512]
//   out     = cumsum(hazards, axis=1) + (x @ W_base^T + b_base)
//
// Round 4: attack cache-BW. Pre-cast x AND W to bf16 (one kernel), GEMM tile
// 64x128 (panel traffic 768->256 MB), bf16 hazards, keep dbuf pipeline +
// XCD bj-fastest swizzle. Fallback to f32-x path if ws too small.

typedef __attribute__((ext_vector_type(8))) short  short8;
typedef __attribute__((ext_vector_type(4))) short  short4v;
typedef __attribute__((ext_vector_type(4))) float  float4v;
typedef __attribute__((ext_vector_type(4))) float  f32x4;

#define DIN  2048
#define DOUT 512
#define NROW 8192
#define NKT  (DIN / 64)
#define XN   (NROW * DIN)   // 16777216
#define WN   (DOUT * DIN)   // 1048576

static __device__ __forceinline__ unsigned short f2bf(float f) {
  union { float f; unsigned int u; } v; v.f = f;
  unsigned int u = v.u;
  unsigned int r = (u + 0x7FFFu + ((u >> 16) & 1u)) >> 16;   // RNE
  return (unsigned short)r;
}
static __device__ __forceinline__ float bf2f(unsigned short u) {
  union { unsigned int u; float f; } v; v.u = ((unsigned int)u) << 16;
  return v.f;
}

// ------------- kernel 1a: cast x [8192][2048] + W [512][2048] -> bf16 ------
__global__ __launch_bounds__(256) void k_cast2(const float* __restrict__ x,
                                               const float* __restrict__ W,
                                               unsigned short* __restrict__ Xb,
                                               unsigned short* __restrict__ Wb) {
  size_t e = ((size_t)blockIdx.x * 256 + threadIdx.x) * 8;
  const float* src;
  unsigned short* dst;
  if (e < (size_t)XN) { src = x + e; dst = Xb + e; }
  else                { src = W + (e - XN); dst = Wb + (e - XN); }
  float4v a = *(const float4v*)src;
  float4v b = *(const float4v*)(src + 4);
  unsigned short o[8] = { f2bf(a.x), f2bf(a.y), f2bf(a.z), f2bf(a.w),
                          f2bf(b.x), f2bf(b.y), f2bf(b.z), f2bf(b.w) };
  *(short8*)dst = *(const short8*)o;
}

// ------------- kernel 1b: cast W only (fallback path) ----------------------
__global__ __launch_bounds__(256) void k_castW(const float* __restrict__ W,
                                               unsigned short* __restrict__ Wb) {
  size_t i = ((size_t)blockIdx.x * 256 + threadIdx.x) * 8;
  float4v a = *(const float4v*)(W + i);
  float4v b = *(const float4v*)(W + i + 4);
  unsigned short o[8] = { f2bf(a.x), f2bf(a.y), f2bf(a.z), f2bf(a.w),
                          f2bf(b.x), f2bf(b.y), f2bf(b.z), f2bf(b.w) };
  *(short8*)(Wb + i) = *(const short8*)o;
}

// ---------------- kernel 2: GEMM + bias + relu + base GEMV -----------------
// tile BM=64 x BN=128, BK=64; 256 threads = 4 waves (2x2), wave tile 32x64.
// LDS XOR-swizzle: 16B granule g of row r stored at g ^ (r&7)   (row = 128B).
// XBF: A loaded pre-cast bf16; else f32 + fused convert.
template <bool XBF>
__global__ __launch_bounds__(256, 2) void k_gemm(
    const float* __restrict__ xf, const unsigned short* __restrict__ Xb,
    const unsigned short* __restrict__ Wb,
    const float* __restrict__ b_h, const float* __restrict__ w_base,
    const float* __restrict__ b_base, unsigned short* __restrict__ hzb,
    float* __restrict__ base_out) {
  __shared__ unsigned short Asw[2][64 * 64];    // 2 x 8 KB
  __shared__ unsigned short Bsw[2][128 * 64];   // 2 x 16 KB
  __shared__ float WbL[DIN];                    // 8 KB (base GEMV weights)

  const int tid  = threadIdx.x;
  const int lane = tid & 63;
  const int wv   = tid >> 6;
  const int wr   = wv >> 1, wc = wv & 1;

  // XCD-chunked bijective swizzle: nwg=512 -> chunk 64 per XCD; bj fastest so
  // the 4 sharers of an A-panel are time/space-adjacent on one XCD (L2 reuse).
  const int id  = blockIdx.x;
  const int swz = ((id & 7) << 6) | (id >> 3);
  const int bi  = swz >> 2;          // 0..127  M-tile
  const int bj  = swz & 3;           // 0..3    N-tile
  const int m0  = bi * 64, n0 = bj * 128;
  const bool do_base = (bj == 0);

  if (do_base) {
    for (int i = tid; i < DIN; i += 256) WbL[i] = w_base[i];
  }

  // A staging: thread t -> row t>>2 (0..63), 16-elem seg (t&3)
  const int sr = tid >> 2;
  const int g0 = (tid & 3) * 2;
  const int offS0 = sr * 64 + (((g0)     ^ (sr & 7)) << 3);
  const int offS1 = sr * 64 + (((g0 + 1) ^ (sr & 7)) << 3);
  // B staging: thread t -> row t>>1 (0..127), 32-elem half (t&1): 4 granules
  const int rB  = tid >> 1;
  const int hB  = tid & 1;
  int offB[4];
#pragma unroll
  for (int p = 0; p < 4; ++p)
    offB[p] = rB * 64 + (((hB * 4 + p) ^ (rB & 7)) << 3);

  f32x4 acc[2][4];
  const f32x4 zero4 = {0.f, 0.f, 0.f, 0.f};
#pragma unroll
  for (int mi = 0; mi < 2; ++mi)
#pragma unroll
    for (int ni = 0; ni < 4; ++ni) acc[mi][ni] = zero4;

  struct Tile { float4v a4[4]; short8 a2[2]; short8 b[4]; };
  Tile t0, t1;

  auto load_tile = [&](Tile& T, int kt) {
    const int k0 = kt * 64;
    if constexpr (XBF) {
      const unsigned short* ap = Xb + (size_t)(m0 + sr) * DIN + k0 + (tid & 3) * 16;
      T.a2[0] = ((const short8*)ap)[0];
      T.a2[1] = ((const short8*)ap)[1];
    } else {
      const float* ap = xf + (size_t)(m0 + sr) * DIN + k0 + (tid & 3) * 16;
#pragma unroll
      for (int p = 0; p < 4; ++p) T.a4[p] = *(const float4v*)(ap + p * 4);
    }
    const short8* bp = (const short8*)(Wb + (size_t)(n0 + rB) * DIN + k0 + hB * 32);
#pragma unroll
    for (int p = 0; p < 4; ++p) T.b[p] = bp[p];
  };

  auto write_tile = [&](unsigned short* As, unsigned short* Bs, const Tile& T) {
    if constexpr (XBF) {
      *(short8*)&As[offS0] = T.a2[0];
      *(short8*)&As[offS1] = T.a2[1];
    } else {
      unsigned short t8[16];
#pragma unroll
      for (int p = 0; p < 4; ++p) {
        t8[p * 4 + 0] = f2bf(T.a4[p].x); t8[p * 4 + 1] = f2bf(T.a4[p].y);
        t8[p * 4 + 2] = f2bf(T.a4[p].z); t8[p * 4 + 3] = f2bf(T.a4[p].w);
      }
      *(short8*)&As[offS0] = *(const short8*)&t8[0];
      *(short8*)&As[offS1] = *(const short8*)&t8[8];
    }
#pragma unroll
    for (int p = 0; p < 4; ++p) *(short8*)&Bs[offB[p]] = T.b[p];
  };

  float basePart = 0.f;
  const int bSeg = tid & 3;  // base GEMV: 4 threads per row (row = sr)

  auto compute = [&](const unsigned short* As, const unsigned short* Bs, int kt) {
#pragma unroll
    for (int kk = 0; kk < 2; ++kk) {
      short8 af[2], bfr[4];
#pragma unroll
      for (int mi = 0; mi < 2; ++mi) {
        int row = wr * 32 + mi * 16 + (lane & 15);
        int gr  = kk * 4 + (lane >> 4);
        af[mi] = *(const short8*)&As[row * 64 + ((gr ^ (row & 7)) << 3)];
      }
#pragma unroll
      for (int ni = 0; ni < 4; ++ni) {
        int col = wc * 64 + ni * 16 + (lane & 15);
        int gr  = kk * 4 + (lane >> 4);
        bfr[ni] = *(const short8*)&Bs[col * 64 + ((gr ^ (col & 7)) << 3)];
      }
      // swapped operands: lane&15 = output row slot, regs = 4 consecutive cols
#pragma unroll
      for (int mi = 0; mi < 2; ++mi)
#pragma unroll
        for (int ni = 0; ni < 4; ++ni)
          acc[mi][ni] = __builtin_amdgcn_mfma_f32_16x16x32_bf16(
              bfr[ni], af[mi], acc[mi][ni], 0, 0, 0);
    }
    if (do_base) {  // base GEMV partial from staged A tile (bf16 precision)
      const int k0 = kt * 64;
      float p = 0.f;
#pragma unroll
      for (int j = 0; j < 2; ++j) {
        int g = bSeg * 2 + j;
        const short8 v = *(const short8*)&As[sr * 64 + ((g ^ (sr & 7)) << 3)];
#pragma unroll
        for (int e = 0; e < 8; ++e)
          p += bf2f((unsigned short)v[e]) * WbL[k0 + bSeg * 16 + j * 8 + e];
      }
      basePart += p;
    }
  };

  // prologue: fill buf0 with tile0; tile1 loads stay in flight
  load_tile(t0, 0);
  load_tile(t1, 1);
  write_tile(Asw[0], Bsw[0], t0);
  __syncthreads();

  for (int kt = 0; kt < NKT; kt += 2) {
    if (kt + 2 < NKT) load_tile(t0, kt + 2);
    compute(Asw[0], Bsw[0], kt);
    if (kt + 1 < NKT) write_tile(Asw[1], Bsw[1], t1);
    __syncthreads();
    if (kt + 3 < NKT) load_tile(t1, kt + 3);
    if (kt + 1 < NKT) compute(Asw[1], Bsw[1], kt + 1);
    if (kt + 2 < NKT) write_tile(Asw[0], Bsw[0], t0);
    __syncthreads();
  }

  if (do_base) {
    float s = basePart;
    s += __shfl_xor(s, 1);
    s += __shfl_xor(s, 2);
    if ((tid & 3) == 0) base_out[m0 + sr] = s + b_base[0];
  }

  // epilogue: bias + relu -> bf16 hazards (regs = 4 consecutive cols)
#pragma unroll
  for (int mi = 0; mi < 2; ++mi) {
    int m = m0 + wr * 32 + mi * 16 + (lane & 15);
#pragma unroll
    for (int ni = 0; ni < 4; ++ni) {
      int nb = n0 + wc * 64 + ni * 16 + ((lane >> 4) << 2);
      float4v b4 = *(const float4v*)(b_h + nb);
      f32x4 v = acc[mi][ni];
      unsigned short h[4] = { f2bf(fmaxf(v.x + b4.x, 0.f)),
                              f2bf(fmaxf(v.y + b4.y, 0.f)),
                              f2bf(fmaxf(v.z + b4.z, 0.f)),
                              f2bf(fmaxf(v.w + b4.w, 0.f)) };
      *(short4v*)(hzb + (size_t)m * DOUT + nb) = *(const short4v*)h;
    }
  }
}

// ---------------- kernel 3: per-row inclusive scan + base ------------------
// 4 waves per block, one row per wave; lane holds 8 consecutive bf16.
__global__ __launch_bounds__(256) void k_scan(const unsigned short* __restrict__ hzb,
                                              const float* __restrict__ base,
                                              float* __restrict__ out) {
  const int tid  = threadIdx.x;
  const int lane = tid & 63;
  const int w    = tid >> 6;
  const int row  = blockIdx.x * 4 + w;

  const short8 v = *(const short8*)(hzb + (size_t)row * DOUT + lane * 8);

  float s0 = bf2f((unsigned short)v[0]);
  float s1 = s0 + bf2f((unsigned short)v[1]);
  float s2 = s1 + bf2f((unsigned short)v[2]);
  float s3 = s2 + bf2f((unsigned short)v[3]);
  float s4 = s3 + bf2f((unsigned short)v[4]);
  float s5 = s4 + bf2f((unsigned short)v[5]);
  float s6 = s5 + bf2f((unsigned short)v[6]);
  float s7 = s6 + bf2f((unsigned short)v[7]);

  float T = s7, sc = s7;
#pragma unroll
  for (int d = 1; d < 64; d <<= 1) {
    float t = __shfl_up(sc, d);
    if (lane >= d) sc += t;
  }
  float off = sc - T + base[row];

  float4v o0 = { s0 + off, s1 + off, s2 + off, s3 + off };
  float4v o1 = { s4 + off, s5 + off, s6 + off, s7 + off };
  float* q = out + (size_t)row * DOUT + lane * 8;
  *(float4v*)q       = o0;
  *(float4v*)(q + 4) = o1;
}

// ---------------------------------------------------------------------------
extern "C" void kernel_launch(void* const* d_in, const int* in_sizes, int n_in,
                              void* d_out, int out_size, void* d_ws, size_t ws_size,
                              hipStream_t stream) {
  const float* x   = (const float*)d_in[0];  // [8192,2048]
  const float* Wh  = (const float*)d_in[1];  // [512,2048]
  const float* bh  = (const float*)d_in[2];  // [512]
  const float* Wb0 = (const float*)d_in[3];  // [1,2048]
  const float* bb  = (const float*)d_in[4];  // [1]
  float* out = (float*)d_out;

  char* ws = (char*)d_ws;
  const size_t MB = 1024u * 1024u;
  // precast layout: Wb 2MB | Xb 32MB | base 1MB | hzb 8MB  = 43MB
  // fallback:       Wb 2MB | base 1MB | hzb 8MB            = 11MB
  const bool precast = ws_size >= 44u * MB;

  unsigned short* Wbf = (unsigned short*)ws;
  if (precast) {
    unsigned short* Xbf = (unsigned short*)(ws + 2 * MB);
    float* base         = (float*)(ws + 34 * MB);
    unsigned short* hzb = (unsigned short*)(ws + 35 * MB);
    k_cast2<<<dim3((XN + WN) / (256 * 8)), dim3(256), 0, stream>>>(x, Wh, Xbf, Wbf);
    k_gemm<true><<<dim3(512), dim3(256), 0, stream>>>(x, Xbf, Wbf, bh, Wb0, bb, hzb, base);
    k_scan<<<dim3(NROW / 4), dim3(256), 0, stream>>>(hzb, base, out);
  } else {
    float* base         = (float*)(ws + 2 * MB);
    unsigned short* hzb = (unsigned short*)(ws + 3 * MB);
    k_castW<<<dim3(WN / (256 * 8)), dim3(256), 0, stream>>>(Wh, Wbf);
    k_gemm<false><<<dim3(512), dim3(256), 0, stream>>>(x, (const unsigned short*)nullptr,
                                                       Wbf, bh, Wb0, bb, hzb, base);
    k_scan<<<dim3(NROW / 4), dim3(256), 0, stream>>>(hzb, base, out);
  }
}

// Round 5
// 46.878 us; speedup vs baseline: 1.3771x; 1.2733x over previous
//
#include <hip/hip_runtime.h>
#include <hip/hip_bf16.h>

// Problem: B=8192, DIM_IN=2048, DIM_OUT=512
//   hazards = relu(x @ W_h^T + b_h)            [8192,512]
//   out     = cumsum(hazards, axis=1) + (x @ W_base^T + b_base)
//
// Round 5: single fused GEMM+scan kernel. BM=32, BN=512(=DOUT), BK=64.
// W pre-packed to MFMA-fragment layout (L2-resident, loaded direct to regs,
// no LDS for B). A (x) staged f32->bf16 through tiny dbuf LDS. Epilogue does
// bias+relu+row-scan+base in-register with one LDS strip-carry.

typedef __attribute__((ext_vector_type(8))) short  short8;
typedef __attribute__((ext_vector_type(4))) short  short4v;
typedef __attribute__((ext_vector_type(4))) float  float4v;
typedef __attribute__((ext_vector_type(4))) float  f32x4;

#define DIN  2048
#define DOUT 512
#define NROW 8192
#define BM   32
#define NPH  (DIN / 64)   // 32 K-phases of 64

static __device__ __forceinline__ unsigned short f2bf(float f) {
  union { float f; unsigned int u; } v; v.f = f;
  unsigned int u = v.u;
  unsigned int r = (u + 0x7FFFu + ((u >> 16) & 1u)) >> 16;   // RNE
  return (unsigned short)r;
}

// ---- k_pack: W[512][2048] f32 -> fragment-packed bf16 ---------------------
// fragment (nt, ktp): nt = n>>4 (32), ktp = k>>5 (64).
// lane slot: n = nt*16 + (lane&15), k = ktp*32 + (lane>>4)*8 (+e, e=0..7)
// storage: Wp[ ((nt*64 + ktp)*64 + lane)*8 + e ]  -> wave load = 1KB contig.
__global__ __launch_bounds__(256) void k_pack(const float* __restrict__ W,
                                              unsigned short* __restrict__ Wp) {
  int t    = blockIdx.x * 256 + threadIdx.x;   // 0..131071
  int lane = t & 63;
  int frag = t >> 6;
  int nt   = frag >> 6, ktp = frag & 63;
  int n = nt * 16 + (lane & 15);
  int k = ktp * 32 + (lane >> 4) * 8;
  const float* src = W + (size_t)n * DIN + k;
  float4v a = *(const float4v*)src;
  float4v b = *(const float4v*)(src + 4);
  unsigned short o[8] = { f2bf(a.x), f2bf(a.y), f2bf(a.z), f2bf(a.w),
                          f2bf(b.x), f2bf(b.y), f2bf(b.z), f2bf(b.w) };
  *(short8*)(Wp + (size_t)t * 8) = *(const short8*)o;
}

// ---- k_main: fused GEMM + bias + relu + row-scan + base -------------------
// grid 256 (BM=32 rows each), 512 threads = 8 waves; wave w owns cols
// 64w..64w+63 (ni 0..3 -> nt = 4w+ni). acc[mi][ni]: rows mi*16+(lane&15),
// cols ni*16 + (lane>>4)*4 + reg.   (swapped mfma: D[n][m], col slot = m)
__global__ __launch_bounds__(512, 2) void k_main(
    const float* __restrict__ x, const unsigned short* __restrict__ Wp,
    const float* __restrict__ b_h, const float* __restrict__ w_base,
    const float* __restrict__ b_base, float* __restrict__ out) {
  __shared__ unsigned short Asw[2][BM * 64];   // 2 x 4 KB, XOR-swizzled
  __shared__ float WbL[DIN];                   // 8 KB base-GEMV weights
  __shared__ float stripT[BM][8];              // per-row per-wave strip totals
  __shared__ float baseL[BM];

  const int tid  = threadIdx.x;
  const int lane = tid & 63;
  const int w    = tid >> 6;       // wave 0..7
  const int q    = lane >> 4;      // 0..3
  const int lm   = lane & 15;
  const int m0   = blockIdx.x * BM;

  // A staging: thread -> row sr = tid>>4 (0..31), seg = tid&15 (4 f32)
  const int sr  = tid >> 4;
  const int seg = tid & 15;
  const int sOff = sr * 64 + (((seg >> 1) ^ (sr & 7)) << 3) + (seg & 1) * 4;

  for (int i = tid; i < DIN; i += 512) WbL[i] = w_base[i];

  f32x4 acc[2][4];
  const f32x4 z4 = {0.f, 0.f, 0.f, 0.f};
#pragma unroll
  for (int mi = 0; mi < 2; ++mi)
#pragma unroll
    for (int ni = 0; ni < 4; ++ni) acc[mi][ni] = z4;

  float4v a0, a1;
  short8  wf0[4][2], wf1[4][2];
  float   basePart = 0.f;

  auto loadA = [&](float4v& A, int kt) {
    A = *(const float4v*)(x + (size_t)(m0 + sr) * DIN + kt * 64 + seg * 4);
  };
  auto loadB = [&](short8 wf[4][2], int kt) {
#pragma unroll
    for (int ni = 0; ni < 4; ++ni)
#pragma unroll
      for (int h = 0; h < 2; ++h) {
        int frag = (w * 4 + ni) * 64 + (kt * 2 + h);
        wf[ni][h] = *(const short8*)(Wp + ((size_t)frag << 9) + lane * 8);
      }
  };
  auto writeA = [&](unsigned short* As, const float4v& A, int kt) {
    unsigned short t4[4] = { f2bf(A.x), f2bf(A.y), f2bf(A.z), f2bf(A.w) };
    *(short4v*)&As[sOff] = *(const short4v*)t4;
    float4v wb = *(const float4v*)&WbL[kt * 64 + seg * 4];
    basePart += A.x * wb.x + A.y * wb.y + A.z * wb.z + A.w * wb.w;
  };
  auto compute = [&](const unsigned short* As, const short8 wf[4][2]) {
#pragma unroll
    for (int h = 0; h < 2; ++h) {
      short8 xf[2];
#pragma unroll
      for (int mi = 0; mi < 2; ++mi) {
        int r = mi * 16 + lm;
        int g = q + 4 * h;
        xf[mi] = *(const short8*)&As[r * 64 + ((g ^ (r & 7)) << 3)];
      }
#pragma unroll
      for (int mi = 0; mi < 2; ++mi)
#pragma unroll
        for (int ni = 0; ni < 4; ++ni)
          acc[mi][ni] = __builtin_amdgcn_mfma_f32_16x16x32_bf16(
              wf[ni][h], xf[mi], acc[mi][ni], 0, 0, 0);
    }
  };

  // prologue
  loadA(a0, 0); loadB(wf0, 0);
  loadA(a1, 1); loadB(wf1, 1);
  __syncthreads();                 // WbL ready
  writeA(Asw[0], a0, 0);
  __syncthreads();                 // tile 0 staged

  for (int kt = 0; kt < NPH; kt += 2) {
    // phase A: compute tile kt from buf0 + wf0
    if (kt + 2 < NPH) loadA(a0, kt + 2);
    compute(Asw[0], wf0);
    if (kt + 2 < NPH) loadB(wf0, kt + 2);
    writeA(Asw[1], a1, kt + 1);                  // kt+1 <= 31 always
    __syncthreads();
    // phase B: compute tile kt+1 from buf1 + wf1
    if (kt + 3 < NPH) loadA(a1, kt + 3);
    compute(Asw[1], wf1);
    if (kt + 3 < NPH) loadB(wf1, kt + 3);
    if (kt + 2 < NPH) writeA(Asw[0], a0, kt + 2);
    __syncthreads();
  }

  // ---- base GEMV reduce: 16 consecutive lanes share row sr ----
  {
    float s = basePart;
    s += __shfl_xor(s, 1); s += __shfl_xor(s, 2);
    s += __shfl_xor(s, 4); s += __shfl_xor(s, 8);
    if (seg == 0) baseL[sr] = s + b_base[0];
  }

  // ---- epilogue: bias + relu + scan over this wave's 64-col strip ----
  float runp[2][4][4];   // inclusive in-run (4-col) prefix
  float Eq[2][4];        // sum of runs with smaller q (same 16-col group)
  float niPre[2][4];     // sum of full 16-col groups with smaller ni
  float Tst[2];          // strip total per row
#pragma unroll
  for (int mi = 0; mi < 2; ++mi) {
    float run = 0.f;
#pragma unroll
    for (int ni = 0; ni < 4; ++ni) {
      float4v b4 = *(const float4v*)(b_h + w * 64 + ni * 16 + q * 4);
      f32x4 v = acc[mi][ni];
      float h0 = fmaxf(v.x + b4.x, 0.f);
      float h1 = fmaxf(v.y + b4.y, 0.f);
      float h2 = fmaxf(v.z + b4.z, 0.f);
      float h3 = fmaxf(v.w + b4.w, 0.f);
      runp[mi][ni][0] = h0;
      runp[mi][ni][1] = h0 + h1;
      runp[mi][ni][2] = h0 + h1 + h2;
      runp[mi][ni][3] = h0 + h1 + h2 + h3;
      float S = runp[mi][ni][3];
      float u1 = __shfl_up(S, 16);
      float u2 = __shfl_up(S, 32);
      float u3 = __shfl_up(S, 48);
      Eq[mi][ni] = (q >= 1 ? u1 : 0.f) + (q >= 2 ? u2 : 0.f) + (q >= 3 ? u3 : 0.f);
      float G = S + __shfl_xor(S, 16);
      G += __shfl_xor(G, 32);
      niPre[mi][ni] = run;
      run += G;
    }
    Tst[mi] = run;
  }
  if (q == 0) {
#pragma unroll
    for (int mi = 0; mi < 2; ++mi) stripT[mi * 16 + lm][w] = Tst[mi];
  }
  __syncthreads();

#pragma unroll
  for (int mi = 0; mi < 2; ++mi) {
    const int row = mi * 16 + lm;
    float c = baseL[row];
    float4v sA = *(const float4v*)&stripT[row][0];
    float4v sB = *(const float4v*)&stripT[row][4];
    c += (w > 0 ? sA.x : 0.f) + (w > 1 ? sA.y : 0.f) + (w > 2 ? sA.z : 0.f) +
         (w > 3 ? sA.w : 0.f) + (w > 4 ? sB.x : 0.f) + (w > 5 ? sB.y : 0.f) +
         (w > 6 ? sB.z : 0.f);
#pragma unroll
    for (int ni = 0; ni < 4; ++ni) {
      float base = c + niPre[mi][ni] + Eq[mi][ni];
      float4v o = { runp[mi][ni][0] + base, runp[mi][ni][1] + base,
                    runp[mi][ni][2] + base, runp[mi][ni][3] + base };
      *(float4v*)(out + (size_t)(m0 + row) * DOUT + w * 64 + ni * 16 + q * 4) = o;
    }
  }
}

// ---------------------------------------------------------------------------
extern "C" void kernel_launch(void* const* d_in, const int* in_sizes, int n_in,
                              void* d_out, int out_size, void* d_ws, size_t ws_size,
                              hipStream_t stream) {
  const float* x   = (const float*)d_in[0];  // [8192,2048]
  const float* Wh  = (const float*)d_in[1];  // [512,2048]
  const float* bh  = (const float*)d_in[2];  // [512]
  const float* Wb0 = (const float*)d_in[3];  // [1,2048]
  const float* bb  = (const float*)d_in[4];  // [1]
  float* out = (float*)d_out;

  unsigned short* Wp = (unsigned short*)d_ws;   // 2 MiB fragment-packed W

  k_pack<<<dim3((DOUT * DIN) / (256 * 8)), dim3(256), 0, stream>>>(Wh, Wp);
  k_main<<<dim3(NROW / BM), dim3(512), 0, stream>>>(x, Wp, bh, Wb0, bb, out);
}

// Round 6
// 46.718 us; speedup vs baseline: 1.3818x; 1.0034x over previous
//
#include <hip/hip_runtime.h>
#include <hip/hip_bf16.h>

// Problem: B=8192, DIM_IN=2048, DIM_OUT=512
//   hazards = relu(x @ W_h^T + b_h)            [8192,512]
//   out     = cumsum(hazards, axis=1) + (x @ W_base^T + b_base)
//
// Round 6: round-5 fused kernel + NO-DRAIN barriers (lgkmcnt(0)+s_barrier
// instead of __syncthreads, which drains vmcnt(0) and exposes every prefetch
// latency). Global loads now stay in flight across barriers; compiler emits
// counted vmcnt for their uses.

typedef __attribute__((ext_vector_type(8))) short  short8;
typedef __attribute__((ext_vector_type(4))) short  short4v;
typedef __attribute__((ext_vector_type(4))) float  float4v;
typedef __attribute__((ext_vector_type(4))) float  f32x4;

#define DIN  2048
#define DOUT 512
#define NROW 8192
#define BM   32
#define NPH  (DIN / 64)   // 32 K-phases of 64

static __device__ __forceinline__ unsigned short f2bf(float f) {
  union { float f; unsigned int u; } v; v.f = f;
  unsigned int u = v.u;
  unsigned int r = (u + 0x7FFFu + ((u >> 16) & 1u)) >> 16;   // RNE
  return (unsigned short)r;
}

// barrier WITHOUT the vmcnt(0) drain __syncthreads would emit: make LDS
// writes visible (lgkmcnt) but leave global loads in flight (T4).
static __device__ __forceinline__ void barrier_nd() {
  asm volatile("s_waitcnt lgkmcnt(0)" ::: "memory");
  __builtin_amdgcn_s_barrier();
}

// ---- k_pack: W[512][2048] f32 -> fragment-packed bf16 ---------------------
// fragment (nt, ktp): nt = n>>4 (32), ktp = k>>5 (64).
// lane slot: n = nt*16 + (lane&15), k = ktp*32 + (lane>>4)*8 (+e, e=0..7)
// storage: Wp[ ((nt*64 + ktp)*64 + lane)*8 + e ]  -> wave load = 1KB contig.
__global__ __launch_bounds__(256) void k_pack(const float* __restrict__ W,
                                              unsigned short* __restrict__ Wp) {
  int t    = blockIdx.x * 256 + threadIdx.x;   // 0..131071
  int lane = t & 63;
  int frag = t >> 6;
  int nt   = frag >> 6, ktp = frag & 63;
  int n = nt * 16 + (lane & 15);
  int k = ktp * 32 + (lane >> 4) * 8;
  const float* src = W + (size_t)n * DIN + k;
  float4v a = *(const float4v*)src;
  float4v b = *(const float4v*)(src + 4);
  unsigned short o[8] = { f2bf(a.x), f2bf(a.y), f2bf(a.z), f2bf(a.w),
                          f2bf(b.x), f2bf(b.y), f2bf(b.z), f2bf(b.w) };
  *(short8*)(Wp + (size_t)t * 8) = *(const short8*)o;
}

// ---- k_main: fused GEMM + bias + relu + row-scan + base -------------------
// grid 256 (BM=32 rows each), 512 threads = 8 waves; wave w owns cols
// 64w..64w+63 (ni 0..3 -> nt = 4w+ni). acc[mi][ni]: rows mi*16+(lane&15),
// cols ni*16 + (lane>>4)*4 + reg.   (swapped mfma: D[n][m], col slot = m)
__global__ __launch_bounds__(512, 2) void k_main(
    const float* __restrict__ x, const unsigned short* __restrict__ Wp,
    const float* __restrict__ b_h, const float* __restrict__ w_base,
    const float* __restrict__ b_base, float* __restrict__ out) {
  __shared__ unsigned short Asw[2][BM * 64];   // 2 x 4 KB, XOR-swizzled
  __shared__ float WbL[DIN];                   // 8 KB base-GEMV weights
  __shared__ float stripT[BM][8];              // per-row per-wave strip totals
  __shared__ float baseL[BM];

  const int tid  = threadIdx.x;
  const int lane = tid & 63;
  const int w    = tid >> 6;       // wave 0..7
  const int q    = lane >> 4;      // 0..3
  const int lm   = lane & 15;
  const int m0   = blockIdx.x * BM;

  // A staging: thread -> row sr = tid>>4 (0..31), seg = tid&15 (4 f32)
  const int sr  = tid >> 4;
  const int seg = tid & 15;
  const int sOff = sr * 64 + (((seg >> 1) ^ (sr & 7)) << 3) + (seg & 1) * 4;

  for (int i = tid; i < DIN; i += 512) WbL[i] = w_base[i];

  f32x4 acc[2][4];
  const f32x4 z4 = {0.f, 0.f, 0.f, 0.f};
#pragma unroll
  for (int mi = 0; mi < 2; ++mi)
#pragma unroll
    for (int ni = 0; ni < 4; ++ni) acc[mi][ni] = z4;

  float4v a0, a1;
  short8  wf0[4][2], wf1[4][2];
  float   basePart = 0.f;

  auto loadA = [&](float4v& A, int kt) {
    A = *(const float4v*)(x + (size_t)(m0 + sr) * DIN + kt * 64 + seg * 4);
  };
  auto loadB = [&](short8 wf[4][2], int kt) {
#pragma unroll
    for (int ni = 0; ni < 4; ++ni)
#pragma unroll
      for (int h = 0; h < 2; ++h) {
        int frag = (w * 4 + ni) * 64 + (kt * 2 + h);
        wf[ni][h] = *(const short8*)(Wp + ((size_t)frag << 9) + lane * 8);
      }
  };
  auto writeA = [&](unsigned short* As, const float4v& A, int kt) {
    unsigned short t4[4] = { f2bf(A.x), f2bf(A.y), f2bf(A.z), f2bf(A.w) };
    *(short4v*)&As[sOff] = *(const short4v*)t4;
    float4v wb = *(const float4v*)&WbL[kt * 64 + seg * 4];
    basePart += A.x * wb.x + A.y * wb.y + A.z * wb.z + A.w * wb.w;
  };
  auto compute = [&](const unsigned short* As, const short8 wf[4][2]) {
#pragma unroll
    for (int h = 0; h < 2; ++h) {
      short8 xf[2];
#pragma unroll
      for (int mi = 0; mi < 2; ++mi) {
        int r = mi * 16 + lm;
        int g = q + 4 * h;
        xf[mi] = *(const short8*)&As[r * 64 + ((g ^ (r & 7)) << 3)];
      }
#pragma unroll
      for (int mi = 0; mi < 2; ++mi)
#pragma unroll
        for (int ni = 0; ni < 4; ++ni)
          acc[mi][ni] = __builtin_amdgcn_mfma_f32_16x16x32_bf16(
              wf[ni][h], xf[mi], acc[mi][ni], 0, 0, 0);
    }
  };

  // prologue
  loadA(a0, 0); loadB(wf0, 0);
  loadA(a1, 1); loadB(wf1, 1);
  barrier_nd();                    // WbL ready (prefetches stay in flight)
  writeA(Asw[0], a0, 0);
  barrier_nd();                    // tile 0 staged

  for (int kt = 0; kt < NPH; kt += 2) {
    // phase A: compute tile kt from buf0 + wf0
    if (kt + 2 < NPH) loadA(a0, kt + 2);
    compute(Asw[0], wf0);
    if (kt + 2 < NPH) loadB(wf0, kt + 2);
    writeA(Asw[1], a1, kt + 1);                  // kt+1 <= 31 always
    barrier_nd();
    // phase B: compute tile kt+1 from buf1 + wf1
    if (kt + 3 < NPH) loadA(a1, kt + 3);
    compute(Asw[1], wf1);
    if (kt + 3 < NPH) loadB(wf1, kt + 3);
    if (kt + 2 < NPH) writeA(Asw[0], a0, kt + 2);
    barrier_nd();
  }

  // ---- base GEMV reduce: 16 consecutive lanes share row sr ----
  {
    float s = basePart;
    s += __shfl_xor(s, 1); s += __shfl_xor(s, 2);
    s += __shfl_xor(s, 4); s += __shfl_xor(s, 8);
    if (seg == 0) baseL[sr] = s + b_base[0];
  }

  // ---- epilogue: bias + relu + scan over this wave's 64-col strip ----
  float runp[2][4][4];   // inclusive in-run (4-col) prefix
  float Eq[2][4];        // sum of runs with smaller q (same 16-col group)
  float niPre[2][4];     // sum of full 16-col groups with smaller ni
  float Tst[2];          // strip total per row
#pragma unroll
  for (int mi = 0; mi < 2; ++mi) {
    float run = 0.f;
#pragma unroll
    for (int ni = 0; ni < 4; ++ni) {
      float4v b4 = *(const float4v*)(b_h + w * 64 + ni * 16 + q * 4);
      f32x4 v = acc[mi][ni];
      float h0 = fmaxf(v.x + b4.x, 0.f);
      float h1 = fmaxf(v.y + b4.y, 0.f);
      float h2 = fmaxf(v.z + b4.z, 0.f);
      float h3 = fmaxf(v.w + b4.w, 0.f);
      runp[mi][ni][0] = h0;
      runp[mi][ni][1] = h0 + h1;
      runp[mi][ni][2] = h0 + h1 + h2;
      runp[mi][ni][3] = h0 + h1 + h2 + h3;
      float S = runp[mi][ni][3];
      float u1 = __shfl_up(S, 16);
      float u2 = __shfl_up(S, 32);
      float u3 = __shfl_up(S, 48);
      Eq[mi][ni] = (q >= 1 ? u1 : 0.f) + (q >= 2 ? u2 : 0.f) + (q >= 3 ? u3 : 0.f);
      float G = S + __shfl_xor(S, 16);
      G += __shfl_xor(G, 32);
      niPre[mi][ni] = run;
      run += G;
    }
    Tst[mi] = run;
  }
  if (q == 0) {
#pragma unroll
    for (int mi = 0; mi < 2; ++mi) stripT[mi * 16 + lm][w] = Tst[mi];
  }
  barrier_nd();

#pragma unroll
  for (int mi = 0; mi < 2; ++mi) {
    const int row = mi * 16 + lm;
    float c = baseL[row];
    float4v sA = *(const float4v*)&stripT[row][0];
    float4v sB = *(const float4v*)&stripT[row][4];
    c += (w > 0 ? sA.x : 0.f) + (w > 1 ? sA.y : 0.f) + (w > 2 ? sA.z : 0.f) +
         (w > 3 ? sA.w : 0.f) + (w > 4 ? sB.x : 0.f) + (w > 5 ? sB.y : 0.f) +
         (w > 6 ? sB.z : 0.f);
#pragma unroll
    for (int ni = 0; ni < 4; ++ni) {
      float base = c + niPre[mi][ni] + Eq[mi][ni];
      float4v o = { runp[mi][ni][0] + base, runp[mi][ni][1] + base,
                    runp[mi][ni][2] + base, runp[mi][ni][3] + base };
      *(float4v*)(out + (size_t)(m0 + row) * DOUT + w * 64 + ni * 16 + q * 4) = o;
    }
  }
}

// ---------------------------------------------------------------------------
extern "C" void kernel_launch(void* const* d_in, const int* in_sizes, int n_in,
                              void* d_out, int out_size, void* d_ws, size_t ws_size,
                              hipStream_t stream) {
  const float* x   = (const float*)d_in[0];  // [8192,2048]
  const float* Wh  = (const float*)d_in[1];  // [512,2048]
  const float* bh  = (const float*)d_in[2];  // [512]
  const float* Wb0 = (const float*)d_in[3];  // [1,2048]
  const float* bb  = (const float*)d_in[4];  // [1]
  float* out = (float*)d_out;

  unsigned short* Wp = (unsigned short*)d_ws;   // 2 MiB fragment-packed W

  k_pack<<<dim3((DOUT * DIN) / (256 * 8)), dim3(256), 0, stream>>>(Wh, Wp);
  k_main<<<dim3(NROW / BM), dim3(512), 0, stream>>>(x, Wp, bh, Wb0, bb, out);
}

// Round 7
// 41.179 us; speedup vs baseline: 1.5677x; 1.1345x over previous
//
#include <hip/hip_runtime.h>
#include <hip/hip_bf16.h>

// Problem: B=8192, DIM_IN=2048, DIM_OUT=512
//   hazards = relu(x @ W_h^T + b_h)            [8192,512]
//   out     = cumsum(hazards, axis=1) + (x @ W_base^T + b_base)
//
// Round 7: same fused design as r5/r6 (BM=32, BN=512, frag-packed W from L2,
// A via tiny dbuf LDS, fused scan epilogue) but 16 waves/block (1024 thr) =
// 4 waves/SIMD. Rationale: r6 counters (VGPR=72) proved the compiler sinks
// reg-prefetch to its use -> latency-bound at 2 waves/SIMD; double the TLP
// and outstanding loads instead of fighting the scheduler.

typedef __attribute__((ext_vector_type(8))) short  short8;
typedef __attribute__((ext_vector_type(4))) short  short4v;
typedef __attribute__((ext_vector_type(4))) float  float4v;
typedef __attribute__((ext_vector_type(4))) float  f32x4;

#define DIN  2048
#define DOUT 512
#define NROW 8192
#define BM   32
#define NPH  (DIN / 64)   // 32 K-phases of 64

static __device__ __forceinline__ unsigned short f2bf(float f) {
  union { float f; unsigned int u; } v; v.f = f;
  unsigned int u = v.u;
  unsigned int r = (u + 0x7FFFu + ((u >> 16) & 1u)) >> 16;   // RNE
  return (unsigned short)r;
}

// barrier WITHOUT the vmcnt(0) drain __syncthreads would emit
static __device__ __forceinline__ void barrier_nd() {
  asm volatile("s_waitcnt lgkmcnt(0)" ::: "memory");
  __builtin_amdgcn_s_barrier();
}

// ---- k_pack: W[512][2048] f32 -> fragment-packed bf16 ---------------------
// fragment (nt, ktp): nt = n>>4 (32), ktp = k>>5 (64).
// lane slot: n = nt*16 + (lane&15), k = ktp*32 + (lane>>4)*8 (+e)
// storage: Wp[ ((nt*64 + ktp)*64 + lane)*8 + e ]  -> wave load = 1KB contig.
__global__ __launch_bounds__(256) void k_pack(const float* __restrict__ W,
                                              unsigned short* __restrict__ Wp) {
  int t    = blockIdx.x * 256 + threadIdx.x;   // 0..131071
  int lane = t & 63;
  int frag = t >> 6;
  int nt   = frag >> 6, ktp = frag & 63;
  int n = nt * 16 + (lane & 15);
  int k = ktp * 32 + (lane >> 4) * 8;
  const float* src = W + (size_t)n * DIN + k;
  float4v a = *(const float4v*)src;
  float4v b = *(const float4v*)(src + 4);
  unsigned short o[8] = { f2bf(a.x), f2bf(a.y), f2bf(a.z), f2bf(a.w),
                          f2bf(b.x), f2bf(b.y), f2bf(b.z), f2bf(b.w) };
  *(short8*)(Wp + (size_t)t * 8) = *(const short8*)o;
}

// ---- k_main: fused GEMM + bias + relu + row-scan + base -------------------
// grid 256 (BM=32 rows each), 1024 threads = 16 waves; wave w owns cols
// 32w..32w+31 (ni 0..1 -> nt = 2w+ni). acc[mi][ni]: rows mi*16+(lane&15),
// cols ni*16 + (lane>>4)*4 + reg.   (swapped mfma: D[n][m], col slot = m)
__global__ __launch_bounds__(1024, 4) void k_main(
    const float* __restrict__ x, const unsigned short* __restrict__ Wp,
    const float* __restrict__ b_h, const float* __restrict__ w_base,
    const float* __restrict__ b_base, float* __restrict__ out) {
  __shared__ unsigned short Asw[2][BM * 64];   // 2 x 4 KB, XOR-swizzled
  __shared__ float WbL[DIN];                   // 8 KB base-GEMV weights
  __shared__ float stripT[BM][16];             // per-row per-wave strip totals
  __shared__ float baseL[BM];

  const int tid  = threadIdx.x;
  const int lane = tid & 63;
  const int w    = tid >> 6;       // wave 0..15
  const int q    = lane >> 4;      // 0..3
  const int lm   = lane & 15;
  const int m0   = blockIdx.x * BM;
  const bool stager = (tid < 512); // waves 0..7 stage A + base GEMV

  // A staging (tid<512): row sr = tid>>4 (0..31), seg = tid&15 (4 f32)
  const int sr  = tid >> 4;
  const int seg = tid & 15;
  const int sOff = (sr & 31) * 64 + (((seg >> 1) ^ (sr & 7)) << 3) + (seg & 1) * 4;

  for (int i = tid; i < DIN; i += 1024) WbL[i] = w_base[i];

  f32x4 acc[2][2];
  const f32x4 z4 = {0.f, 0.f, 0.f, 0.f};
#pragma unroll
  for (int mi = 0; mi < 2; ++mi)
#pragma unroll
    for (int ni = 0; ni < 2; ++ni) acc[mi][ni] = z4;

  float4v a0, a1;
  short8  wf0[2][2], wf1[2][2];
  float   basePart = 0.f;

  auto loadA = [&](float4v& A, int kt) {
    if (stager)
      A = *(const float4v*)(x + (size_t)(m0 + sr) * DIN + kt * 64 + seg * 4);
  };
  auto loadB = [&](short8 wf[2][2], int kt) {
#pragma unroll
    for (int ni = 0; ni < 2; ++ni)
#pragma unroll
      for (int h = 0; h < 2; ++h) {
        int frag = (w * 2 + ni) * 64 + (kt * 2 + h);
        wf[ni][h] = *(const short8*)(Wp + ((size_t)frag << 9) + lane * 8);
      }
  };
  auto writeA = [&](unsigned short* As, const float4v& A, int kt) {
    if (stager) {
      unsigned short t4[4] = { f2bf(A.x), f2bf(A.y), f2bf(A.z), f2bf(A.w) };
      *(short4v*)&As[sOff] = *(const short4v*)t4;
      float4v wb = *(const float4v*)&WbL[kt * 64 + seg * 4];
      basePart += A.x * wb.x + A.y * wb.y + A.z * wb.z + A.w * wb.w;
    }
  };
  auto compute = [&](const unsigned short* As, const short8 wf[2][2]) {
#pragma unroll
    for (int h = 0; h < 2; ++h) {
      short8 xf[2];
#pragma unroll
      for (int mi = 0; mi < 2; ++mi) {
        int r = mi * 16 + lm;
        int g = q + 4 * h;
        xf[mi] = *(const short8*)&As[r * 64 + ((g ^ (r & 7)) << 3)];
      }
#pragma unroll
      for (int mi = 0; mi < 2; ++mi)
#pragma unroll
        for (int ni = 0; ni < 2; ++ni)
          acc[mi][ni] = __builtin_amdgcn_mfma_f32_16x16x32_bf16(
              wf[ni][h], xf[mi], acc[mi][ni], 0, 0, 0);
    }
  };

  // prologue
  loadA(a0, 0); loadB(wf0, 0);
  loadA(a1, 1); loadB(wf1, 1);
  barrier_nd();                    // WbL ready (global prefetches in flight)
  writeA(Asw[0], a0, 0);
  barrier_nd();                    // tile 0 staged

  for (int kt = 0; kt < NPH; kt += 2) {
    // phase A: compute tile kt from buf0 + wf0
    if (kt + 2 < NPH) loadA(a0, kt + 2);
    compute(Asw[0], wf0);
    if (kt + 2 < NPH) loadB(wf0, kt + 2);
    writeA(Asw[1], a1, kt + 1);                  // kt+1 <= 31 always
    barrier_nd();
    // phase B: compute tile kt+1 from buf1 + wf1
    if (kt + 3 < NPH) loadA(a1, kt + 3);
    compute(Asw[1], wf1);
    if (kt + 3 < NPH) loadB(wf1, kt + 3);
    if (kt + 2 < NPH) writeA(Asw[0], a0, kt + 2);
    barrier_nd();
  }

  // ---- base GEMV reduce: 16 consecutive threads share row sr ----
  if (stager) {
    float s = basePart;
    s += __shfl_xor(s, 1); s += __shfl_xor(s, 2);
    s += __shfl_xor(s, 4); s += __shfl_xor(s, 8);
    if (seg == 0) baseL[sr] = s + b_base[0];
  }

  // ---- epilogue: bias + relu + scan over this wave's 32-col strip ----
  float runp[2][2][4];   // inclusive in-run (4-col) prefix
  float Eq[2][2];        // sum of runs with smaller q (same 16-col group)
  float niPre[2][2];     // sum of full 16-col groups with smaller ni
  float Tst[2];          // strip total per row
#pragma unroll
  for (int mi = 0; mi < 2; ++mi) {
    float run = 0.f;
#pragma unroll
    for (int ni = 0; ni < 2; ++ni) {
      float4v b4 = *(const float4v*)(b_h + w * 32 + ni * 16 + q * 4);
      f32x4 v = acc[mi][ni];
      float h0 = fmaxf(v.x + b4.x, 0.f);
      float h1 = fmaxf(v.y + b4.y, 0.f);
      float h2 = fmaxf(v.z + b4.z, 0.f);
      float h3 = fmaxf(v.w + b4.w, 0.f);
      runp[mi][ni][0] = h0;
      runp[mi][ni][1] = h0 + h1;
      runp[mi][ni][2] = h0 + h1 + h2;
      runp[mi][ni][3] = h0 + h1 + h2 + h3;
      float S = runp[mi][ni][3];
      float u1 = __shfl_up(S, 16);
      float u2 = __shfl_up(S, 32);
      float u3 = __shfl_up(S, 48);
      Eq[mi][ni] = (q >= 1 ? u1 : 0.f) + (q >= 2 ? u2 : 0.f) + (q >= 3 ? u3 : 0.f);
      float G = S + __shfl_xor(S, 16);
      G += __shfl_xor(G, 32);
      niPre[mi][ni] = run;
      run += G;
    }
    Tst[mi] = run;
  }
  if (q == 0) {
#pragma unroll
    for (int mi = 0; mi < 2; ++mi) stripT[mi * 16 + lm][w] = Tst[mi];
  }
  barrier_nd();

#pragma unroll
  for (int mi = 0; mi < 2; ++mi) {
    const int row = mi * 16 + lm;
    float c = baseL[row];
#pragma unroll
    for (int j4 = 0; j4 < 4; ++j4) {
      float4v s = *(const float4v*)&stripT[row][j4 * 4];
      c += (w > j4 * 4 + 0 ? s.x : 0.f) + (w > j4 * 4 + 1 ? s.y : 0.f) +
           (w > j4 * 4 + 2 ? s.z : 0.f) + (w > j4 * 4 + 3 ? s.w : 0.f);
    }
#pragma unroll
    for (int ni = 0; ni < 2; ++ni) {
      float base = c + niPre[mi][ni] + Eq[mi][ni];
      float4v o = { runp[mi][ni][0] + base, runp[mi][ni][1] + base,
                    runp[mi][ni][2] + base, runp[mi][ni][3] + base };
      *(float4v*)(out + (size_t)(m0 + row) * DOUT + w * 32 + ni * 16 + q * 4) = o;
    }
  }
}

// ---------------------------------------------------------------------------
extern "C" void kernel_launch(void* const* d_in, const int* in_sizes, int n_in,
                              void* d_out, int out_size, void* d_ws, size_t ws_size,
                              hipStream_t stream) {
  const float* x   = (const float*)d_in[0];  // [8192,2048]
  const float* Wh  = (const float*)d_in[1];  // [512,2048]
  const float* bh  = (const float*)d_in[2];  // [512]
  const float* Wb0 = (const float*)d_in[3];  // [1,2048]
  const float* bb  = (const float*)d_in[4];  // [1]
  float* out = (float*)d_out;

  unsigned short* Wp = (unsigned short*)d_ws;   // 2 MiB fragment-packed W

  k_pack<<<dim3((DOUT * DIN) / (256 * 8)), dim3(256), 0, stream>>>(Wh, Wp);
  k_main<<<dim3(NROW / BM), dim3(1024), 0, stream>>>(x, Wp, bh, Wb0, bb, out);
}